// Round 3
// baseline (34.977 us; speedup 1.0000x reference)
//
#include <hip/hip_runtime.h>

constexpr int NW  = 12;
constexpr int BT  = 512;    // 2 samples x 256 threads; per-sample bits [wave:2][lane:6][local:4]
constexpr int TPS = 256;

struct C2 { float u00r,u00i,u01r,u01i,u10r,u10i,u11r,u11i; };
struct St { float re[16]; float im[16]; };

__device__ __forceinline__ float shx(float v, int m) { return __shfl_xor(v, m, 64); }

// ---- single-qubit gate on a LOCAL bit (pure registers) ----
template<int LM>
__device__ __forceinline__ void gate_local(St& s, const C2& u) {
    #pragma unroll
    for (int j0 = 0; j0 < 16; ++j0) {
        if (j0 & LM) continue;
        const int j1 = j0 | LM;
        float r0=s.re[j0], m0=s.im[j0], r1=s.re[j1], m1=s.im[j1];
        s.re[j0] = u.u00r*r0 - u.u00i*m0 + u.u01r*r1 - u.u01i*m1;
        s.im[j0] = u.u00r*m0 + u.u00i*r0 + u.u01r*m1 + u.u01i*r1;
        s.re[j1] = u.u10r*r0 - u.u10i*m0 + u.u11r*r1 - u.u11i*m1;
        s.im[j1] = u.u10r*m0 + u.u10i*r0 + u.u11r*m1 + u.u11i*r1;
    }
}

// ---- single-qubit gate on a LANE bit (shfl_xor exchange) ----
template<int LMASK>
__device__ __forceinline__ void gate_lane(St& s, const C2& u, int lane) {
    const bool b = (lane & LMASK) != 0;
    const float uar = b ? u.u11r : u.u00r;
    const float uai = b ? u.u11i : u.u00i;
    const float ubr = b ? u.u10r : u.u01r;
    const float ubi = b ? u.u10i : u.u01i;
    #pragma unroll
    for (int j = 0; j < 16; ++j) {
        float pr = shx(s.re[j], LMASK);
        float pi = shx(s.im[j], LMASK);
        float r = s.re[j], m = s.im[j];
        s.re[j] = uar*r - uai*m + ubr*pr - ubi*pi;
        s.im[j] = uar*m + uai*r + ubr*pi + ubi*pr;
    }
}

// ---- single-qubit gate on a WAVE bit (LDS exchange; ONE barrier, caller alternates buffers) ----
template<int WMASK>
__device__ __forceinline__ void gate_wave(St& s, const C2& u, int t, int widl,
                                          float* er, float* ei) {
    #pragma unroll
    for (int j = 0; j < 16; ++j) { er[j*BT + t] = s.re[j]; ei[j*BT + t] = s.im[j]; }
    __syncthreads();
    const int pt = t ^ (WMASK << 6);   // stays within sample (bits 6..7 only)
    const bool b = (widl & WMASK) != 0;
    const float uar = b ? u.u11r : u.u00r;
    const float uai = b ? u.u11i : u.u00i;
    const float ubr = b ? u.u10r : u.u01r;
    const float ubi = b ? u.u10i : u.u01i;
    #pragma unroll
    for (int j = 0; j < 16; ++j) {
        float pr = er[j*BT + pt], pi = ei[j*BT + pt];
        float r = s.re[j], m = s.im[j];
        s.re[j] = uar*r - uai*m + ubr*pr - ubi*pi;
        s.im[j] = uar*m + uai*r + ubr*pi + ubi*pr;
    }
}

// ---- CNOT variants ----
template<int CM, int TM>    // ctrl local, tgt local
__device__ __forceinline__ void cnot_local_local(St& s) {
    #pragma unroll
    for (int j0 = 0; j0 < 16; ++j0) {
        if ((j0 & TM) || !(j0 & CM)) continue;
        const int j1 = j0 | TM;
        float r = s.re[j0]; s.re[j0] = s.re[j1]; s.re[j1] = r;
        float m = s.im[j0]; s.im[j0] = s.im[j1]; s.im[j1] = m;
    }
}

template<int CL, int TM>    // ctrl lane, tgt local
__device__ __forceinline__ void cnot_lane_local(St& s, int lane) {
    const bool c = (lane & CL) != 0;
    #pragma unroll
    for (int j0 = 0; j0 < 16; ++j0) {
        if (j0 & TM) continue;
        const int j1 = j0 | TM;
        float a = s.re[j0], bb = s.re[j1];
        s.re[j0] = c ? bb : a;  s.re[j1] = c ? a : bb;
        float ai = s.im[j0], bi = s.im[j1];
        s.im[j0] = c ? bi : ai; s.im[j1] = c ? ai : bi;
    }
}

template<int CL, int TL>    // ctrl lane, tgt lane
__device__ __forceinline__ void cnot_lane_lane(St& s, int lane) {
    const bool c = (lane & CL) != 0;
    #pragma unroll
    for (int j = 0; j < 16; ++j) {
        float pr = shx(s.re[j], TL), pi = shx(s.im[j], TL);
        s.re[j] = c ? pr : s.re[j];
        s.im[j] = c ? pi : s.im[j];
    }
}

template<int CW, int TL>    // ctrl wave, tgt lane (wave-uniform branch)
__device__ __forceinline__ void cnot_wave_lane(St& s, int widl) {
    if (widl & CW) {
        #pragma unroll
        for (int j = 0; j < 16; ++j) {
            s.re[j] = shx(s.re[j], TL);
            s.im[j] = shx(s.im[j], TL);
        }
    }
}

template<int CM, int WM>    // ctrl local, tgt wave (LDS exchange of ctrl=1 amps; one barrier)
__device__ __forceinline__ void cnot_local_wave(St& s, int t, float* er, float* ei) {
    #pragma unroll
    for (int j = 0; j < 16; ++j) {
        if (!(j & CM)) continue;
        er[j*BT + t] = s.re[j]; ei[j*BT + t] = s.im[j];
    }
    __syncthreads();
    const int pt = t ^ (WM << 6);
    #pragma unroll
    for (int j = 0; j < 16; ++j) {
        if (!(j & CM)) continue;
        s.re[j] = er[j*BT + pt]; s.im[j] = ei[j*BT + pt];
    }
}

template<int CW, int WM>    // ctrl wave, tgt wave (one barrier)
__device__ __forceinline__ void cnot_wave_wave(St& s, int t, int widl, float* er, float* ei) {
    if (widl & CW) {
        #pragma unroll
        for (int j = 0; j < 16; ++j) { er[j*BT+t] = s.re[j]; ei[j*BT+t] = s.im[j]; }
    }
    __syncthreads();
    if (widl & CW) {
        const int pt = t ^ (WM << 6);
        #pragma unroll
        for (int j = 0; j < 16; ++j) { s.re[j] = er[j*BT+pt]; s.im[j] = ei[j*BT+pt]; }
    }
}

__global__ __launch_bounds__(BT)
void qnn_kernel(const float* __restrict__ x, const float* __restrict__ var,
                const float* __restrict__ hw, const float* __restrict__ hb,
                float* __restrict__ out)
{
    // double-buffered exchange LDS: [buf][re/im][j*512 + t] -> 128 KiB
    __shared__ float exch[2][2][16*BT];
    __shared__ float rotu[24][8];
    __shared__ float sxc[2][12], sxs[2][12];
    __shared__ float wavesum[2][4];

    const int t    = threadIdx.x;
    const int ts   = t & (TPS - 1);       // thread within sample
    const int sb   = t >> 8;              // sample within block
    const int b    = blockIdx.x * 2 + sb; // global sample
    const int lane = t & 63;
    const int widl = (t >> 6) & 3;        // sample's wave bits

    // per-block precompute
    if (ts < 12) {
        float sn, cs; sincosf(0.5f * x[b*NW + ts], &sn, &cs);
        sxs[sb][ts] = sn; sxc[sb][ts] = cs;
    }
    if (t < 24) {   // Rot matrices shared across batch — compute once
        const float phi   = var[t*3+0];
        const float theta = var[t*3+1];
        const float omega = var[t*3+2];
        float st, ct; sincosf(0.5f*theta, &st, &ct);
        float sp, cp; sincosf(-0.5f*(phi+omega), &sp, &cp);
        float sm, cm; sincosf(-0.5f*(phi-omega), &sm, &cm);
        rotu[t][0] =  cp*ct; rotu[t][1] =  sp*ct;   // u00
        rotu[t][2] = -cm*st; rotu[t][3] =  sm*st;   // u01
        rotu[t][4] =  cm*st; rotu[t][5] =  sm*st;   // u10
        rotu[t][6] =  cp*ct; rotu[t][7] = -sp*ct;   // u11
    }
    __syncthreads();

    // ---- product-state init after RY encoding: amp(i) = prod_w (bit_w ? s_w : c_w) ----
    St s;
    float F = 1.0f;
    #pragma unroll
    for (int w = 0; w < 8; ++w)
        F *= ((ts >> (7 - w)) & 1) ? sxs[sb][w] : sxc[sb][w];
    #pragma unroll
    for (int j = 0; j < 16; ++j) {
        float v = F;
        v *= (j & 8) ? sxs[sb][8]  : sxc[sb][8];
        v *= (j & 4) ? sxs[sb][9]  : sxc[sb][9];
        v *= (j & 2) ? sxs[sb][10] : sxc[sb][10];
        v *= (j & 1) ? sxs[sb][11] : sxc[sb][11];
        s.re[j] = v; s.im[j] = 0.0f;
    }

    auto ld = [&](int g) -> C2 {
        C2 u;
        u.u00r = rotu[g][0]; u.u00i = rotu[g][1];
        u.u01r = rotu[g][2]; u.u01i = rotu[g][3];
        u.u10r = rotu[g][4]; u.u10i = rotu[g][5];
        u.u11r = rotu[g][6]; u.u11i = rotu[g][7];
        return u;
    };

    #define ROT_SWEEP(base, B0, B1) \
        { C2 u = ld(base+0);  gate_wave<2>(s, u, t, widl, exch[B0][0], exch[B0][1]); } \
        { C2 u = ld(base+1);  gate_wave<1>(s, u, t, widl, exch[B1][0], exch[B1][1]); } \
        { C2 u = ld(base+2);  gate_lane<32>(s, u, lane); } \
        { C2 u = ld(base+3);  gate_lane<16>(s, u, lane); } \
        { C2 u = ld(base+4);  gate_lane<8>(s, u, lane); }  \
        { C2 u = ld(base+5);  gate_lane<4>(s, u, lane); }  \
        { C2 u = ld(base+6);  gate_lane<2>(s, u, lane); }  \
        { C2 u = ld(base+7);  gate_lane<1>(s, u, lane); }  \
        { C2 u = ld(base+8);  gate_local<8>(s, u); } \
        { C2 u = ld(base+9);  gate_local<4>(s, u); } \
        { C2 u = ld(base+10); gate_local<2>(s, u); } \
        { C2 u = ld(base+11); gate_local<1>(s, u); }

    // ================= layer 0 =================
    ROT_SWEEP(0, 0, 1)
    // CNOT ring r=1
    cnot_wave_wave<2,1>(s, t, widl, exch[0][0], exch[0][1]);  // (0,1)
    cnot_wave_lane<1,32>(s, widl);                            // (1,2)
    cnot_lane_lane<32,16>(s, lane);                           // (2,3)
    cnot_lane_lane<16,8>(s, lane);                            // (3,4)
    cnot_lane_lane<8,4>(s, lane);                             // (4,5)
    cnot_lane_lane<4,2>(s, lane);                             // (5,6)
    cnot_lane_lane<2,1>(s, lane);                             // (6,7)
    cnot_lane_local<1,8>(s, lane);                            // (7,8)
    cnot_local_local<8,4>(s);                                 // (8,9)
    cnot_local_local<4,2>(s);                                 // (9,10)
    cnot_local_local<2,1>(s);                                 // (10,11)
    cnot_local_wave<1,2>(s, t, exch[1][0], exch[1][1]);       // (11,0)

    // ================= layer 1 =================
    ROT_SWEEP(12, 0, 1)
    // CNOT ring r=2
    cnot_wave_lane<2,32>(s, widl);                            // (0,2)
    cnot_wave_lane<1,16>(s, widl);                            // (1,3)
    cnot_lane_lane<32,8>(s, lane);                            // (2,4)
    cnot_lane_lane<16,4>(s, lane);                            // (3,5)
    cnot_lane_lane<8,2>(s, lane);                             // (4,6)
    cnot_lane_lane<4,1>(s, lane);                             // (5,7)
    cnot_lane_local<2,8>(s, lane);                            // (6,8)
    cnot_lane_local<1,4>(s, lane);                            // (7,9)
    cnot_local_local<8,2>(s);                                 // (8,10)
    cnot_local_local<4,1>(s);                                 // (9,11)
    cnot_local_wave<2,2>(s, t, exch[0][0], exch[0][1]);       // (10,0)
    cnot_local_wave<1,1>(s, t, exch[1][0], exch[1][1]);       // (11,1)

    #undef ROT_SWEEP

    // ---- probs -> Z expvals -> head, fused ----
    float hwreg[NW];
    #pragma unroll
    for (int w = 0; w < NW; ++w) hwreg[w] = hw[w];
    float zhi = 0.0f;
    #pragma unroll
    for (int w = 0; w < 8; ++w)
        zhi += ((ts >> (7 - w)) & 1) ? -hwreg[w] : hwreg[w];
    float acc = 0.0f;
    #pragma unroll
    for (int j = 0; j < 16; ++j) {
        float pr = s.re[j]*s.re[j] + s.im[j]*s.im[j];
        float z = zhi;
        z += (j & 8) ? -hwreg[8]  : hwreg[8];
        z += (j & 4) ? -hwreg[9]  : hwreg[9];
        z += (j & 2) ? -hwreg[10] : hwreg[10];
        z += (j & 1) ? -hwreg[11] : hwreg[11];
        acc += pr * z;
    }
    #pragma unroll
    for (int off = 32; off > 0; off >>= 1) acc += __shfl_down(acc, off, 64);
    if (lane == 0) wavesum[sb][widl] = acc;
    __syncthreads();
    if (ts == 0)
        out[b] = wavesum[sb][0] + wavesum[sb][1] + wavesum[sb][2] + wavesum[sb][3] + hb[0];
}

extern "C" void kernel_launch(void* const* d_in, const int* in_sizes, int n_in,
                              void* d_out, int out_size, void* d_ws, size_t ws_size,
                              hipStream_t stream) {
    const float* x   = (const float*)d_in[0];
    const float* var = (const float*)d_in[1];
    const float* hw  = (const float*)d_in[2];
    const float* hb  = (const float*)d_in[3];
    float* out = (float*)d_out;
    qnn_kernel<<<out_size / 2, BT, 0, stream>>>(x, var, hw, hb, out);
}

// Round 6
// 28.907 us; speedup vs baseline: 1.2100x; 1.2100x over previous
//
#include <hip/hip_runtime.h>

constexpr int NW = 12;
constexpr int BT = 512;   // 1 sample/block; state bits [wave:3][lane:6][local:3]
constexpr int NA = 8;     // amps per thread

struct C2 { float u00r,u00i,u01r,u01i,u10r,u10i,u11r,u11i; };
struct St { float re[NA]; float im[NA]; };

// DPP cross-lane: full-permutation controls, all lanes valid
template<int CTRL>
__device__ __forceinline__ float dppx(float v) {
    int r = __builtin_amdgcn_update_dpp(0, __builtin_bit_cast(int, v), CTRL, 0xF, 0xF, true);
    return __builtin_bit_cast(float, r);
}

// partner value across lane-xor M.
// M=1,2,8: DPP (VALU pipe). M=4,16: ds_swizzle BitMode. M=32: ds_bpermute via __shfl_xor.
// (R4/R5 lesson: v_permlane*_swap inline-asm with a==b risks register coalescing -> identity;
//  stick to ops with verified semantics.)
template<int M>
__device__ __forceinline__ float lxor(float v) {
    if constexpr (M == 1)      { return dppx<0xB1>(v); }            // quad_perm [1,0,3,2]
    else if constexpr (M == 2) { return dppx<0x4E>(v); }            // quad_perm [2,3,0,1]
    else if constexpr (M == 8) { return dppx<0x128>(v); }           // row_ror:8 == xor 8 (16-lane row)
    else if constexpr (M == 4) {
        int r = __builtin_amdgcn_ds_swizzle(__builtin_bit_cast(int, v), 0x101F); // xor 4
        return __builtin_bit_cast(float, r);
    } else if constexpr (M == 16) {
        int r = __builtin_amdgcn_ds_swizzle(__builtin_bit_cast(int, v), 0x401F); // xor 16
        return __builtin_bit_cast(float, r);
    } else {
        return __shfl_xor(v, 32, 64);                               // crosses 32-lane halves
    }
}

// ---- Rot gate on a local bit (registers) ----
template<int LM>
__device__ __forceinline__ void gate_local(St& s, const C2& u) {
    #pragma unroll
    for (int j0 = 0; j0 < NA; ++j0) {
        if (j0 & LM) continue;
        const int j1 = j0 | LM;
        float r0=s.re[j0], m0=s.im[j0], r1=s.re[j1], m1=s.im[j1];
        s.re[j0] = u.u00r*r0 - u.u00i*m0 + u.u01r*r1 - u.u01i*m1;
        s.im[j0] = u.u00r*m0 + u.u00i*r0 + u.u01r*m1 + u.u01i*r1;
        s.re[j1] = u.u10r*r0 - u.u10i*m0 + u.u11r*r1 - u.u11i*m1;
        s.im[j1] = u.u10r*m0 + u.u10i*r0 + u.u11r*m1 + u.u11i*r1;
    }
}

// ---- Rot gate on a lane bit ----
template<int M>
__device__ __forceinline__ void gate_lane(St& s, const C2& u, int lane) {
    const bool b = (lane & M) != 0;
    const float uar = b ? u.u11r : u.u00r;
    const float uai = b ? u.u11i : u.u00i;
    const float ubr = b ? u.u10r : u.u01r;
    const float ubi = b ? u.u10i : u.u01i;
    #pragma unroll
    for (int j = 0; j < NA; ++j) {
        float pr = lxor<M>(s.re[j]);
        float pi = lxor<M>(s.im[j]);
        float r = s.re[j], m = s.im[j];
        s.re[j] = uar*r - uai*m + ubr*pr - ubi*pi;
        s.im[j] = uar*m + uai*r + ubr*pi + ubi*pr;
    }
}

// ---- Rot gate on a wave bit (float2 LDS exchange, ONE barrier; caller alternates buffers) ----
template<int WM>
__device__ __forceinline__ void gate_wave(St& s, const C2& u, int t, int wid, float2* ex) {
    #pragma unroll
    for (int j = 0; j < NA; ++j) ex[j*BT + t] = make_float2(s.re[j], s.im[j]);
    __syncthreads();
    const int pt = t ^ (WM << 6);
    const bool b = (wid & WM) != 0;
    const float uar = b ? u.u11r : u.u00r;
    const float uai = b ? u.u11i : u.u00i;
    const float ubr = b ? u.u10r : u.u01r;
    const float ubi = b ? u.u10i : u.u01i;
    #pragma unroll
    for (int j = 0; j < NA; ++j) {
        float2 p = ex[j*BT + pt];
        float r = s.re[j], m = s.im[j];
        s.re[j] = uar*r - uai*m + ubr*p.x - ubi*p.y;
        s.im[j] = uar*m + uai*r + ubr*p.y + ubi*p.x;
    }
}

// ---- CNOTs ----
template<int CM, int TM>
__device__ __forceinline__ void cnot_local_local(St& s) {
    #pragma unroll
    for (int j0 = 0; j0 < NA; ++j0) {
        if ((j0 & TM) || !(j0 & CM)) continue;
        const int j1 = j0 | TM;
        float r = s.re[j0]; s.re[j0] = s.re[j1]; s.re[j1] = r;
        float m = s.im[j0]; s.im[j0] = s.im[j1]; s.im[j1] = m;
    }
}

template<int CL, int TM>
__device__ __forceinline__ void cnot_lane_local(St& s, int lane) {
    const bool c = (lane & CL) != 0;
    #pragma unroll
    for (int j0 = 0; j0 < NA; ++j0) {
        if (j0 & TM) continue;
        const int j1 = j0 | TM;
        float a = s.re[j0], bb = s.re[j1];
        s.re[j0] = c ? bb : a;  s.re[j1] = c ? a : bb;
        float ai = s.im[j0], bi = s.im[j1];
        s.im[j0] = c ? bi : ai; s.im[j1] = c ? ai : bi;
    }
}

template<int CL, int TL>
__device__ __forceinline__ void cnot_lane_lane(St& s, int lane) {
    const bool c = (lane & CL) != 0;
    #pragma unroll
    for (int j = 0; j < NA; ++j) {
        float pr = lxor<TL>(s.re[j]);
        float pi = lxor<TL>(s.im[j]);
        s.re[j] = c ? pr : s.re[j];
        s.im[j] = c ? pi : s.im[j];
    }
}

template<int CW, int TL>
__device__ __forceinline__ void cnot_wave_lane(St& s, int wid) {
    if (wid & CW) {     // wave-uniform branch: all 64 lanes active inside
        #pragma unroll
        for (int j = 0; j < NA; ++j) {
            s.re[j] = lxor<TL>(s.re[j]);
            s.im[j] = lxor<TL>(s.im[j]);
        }
    }
}

template<int CM, int WM>
__device__ __forceinline__ void cnot_local_wave(St& s, int t, float2* ex) {
    #pragma unroll
    for (int j = 0; j < NA; ++j) {
        if (!(j & CM)) continue;
        ex[j*BT + t] = make_float2(s.re[j], s.im[j]);
    }
    __syncthreads();
    const int pt = t ^ (WM << 6);
    #pragma unroll
    for (int j = 0; j < NA; ++j) {
        if (!(j & CM)) continue;
        float2 p = ex[j*BT + pt];
        s.re[j] = p.x; s.im[j] = p.y;
    }
}

template<int CW, int TW>
__device__ __forceinline__ void cnot_wave_wave(St& s, int t, int wid, float2* ex) {
    if (wid & CW) {
        #pragma unroll
        for (int j = 0; j < NA; ++j) ex[j*BT + t] = make_float2(s.re[j], s.im[j]);
    }
    __syncthreads();
    if (wid & CW) {
        const int pt = t ^ (TW << 6);
        #pragma unroll
        for (int j = 0; j < NA; ++j) {
            float2 p = ex[j*BT + pt];
            s.re[j] = p.x; s.im[j] = p.y;
        }
    }
}

__global__ __launch_bounds__(BT)
void qnn_kernel(const float* __restrict__ x, const float* __restrict__ var,
                const float* __restrict__ hw, const float* __restrict__ hb,
                float* __restrict__ out)
{
    // two alternating exchange buffers: 2 x 8j x 512t x float2 = 64 KiB
    // (R3 lesson: keep total LDS <= ~78 KiB so 2 blocks/CU fit)
    __shared__ float2 ex[2][NA * BT];
    __shared__ float rotu[24][8];
    __shared__ float sxc[12], sxs[12];
    __shared__ float wavesum[8];

    const int t    = threadIdx.x;
    const int b    = blockIdx.x;
    const int lane = t & 63;
    const int wid  = t >> 6;

    if (t < 12) {
        float sn, cs; sincosf(0.5f * x[b*NW + t], &sn, &cs);
        sxs[t] = sn; sxc[t] = cs;
    }
    if (t < 24) {
        const float phi   = var[t*3+0];
        const float theta = var[t*3+1];
        const float omega = var[t*3+2];
        float st, ct; sincosf(0.5f*theta, &st, &ct);
        float sp, cp; sincosf(-0.5f*(phi+omega), &sp, &cp);
        float sm, cm; sincosf(-0.5f*(phi-omega), &sm, &cm);
        rotu[t][0] =  cp*ct; rotu[t][1] =  sp*ct;   // u00
        rotu[t][2] = -cm*st; rotu[t][3] =  sm*st;   // u01
        rotu[t][4] =  cm*st; rotu[t][5] =  sm*st;   // u10
        rotu[t][6] =  cp*ct; rotu[t][7] = -sp*ct;   // u11
    }
    __syncthreads();

    // product state after RY encoding: i = t*8 + j; wire w <-> bit 11-w
    St s;
    float F = 1.0f;
    #pragma unroll
    for (int w = 0; w < 9; ++w)
        F *= ((t >> (8 - w)) & 1) ? sxs[w] : sxc[w];
    #pragma unroll
    for (int j = 0; j < NA; ++j) {
        float v = F;
        v *= (j & 4) ? sxs[9]  : sxc[9];
        v *= (j & 2) ? sxs[10] : sxc[10];
        v *= (j & 1) ? sxs[11] : sxc[11];
        s.re[j] = v; s.im[j] = 0.0f;
    }

    auto ld = [&](int g) -> C2 {
        C2 u;
        u.u00r = rotu[g][0]; u.u00i = rotu[g][1];
        u.u01r = rotu[g][2]; u.u01i = rotu[g][3];
        u.u10r = rotu[g][4]; u.u10i = rotu[g][5];
        u.u11r = rotu[g][6]; u.u11i = rotu[g][7];
        return u;
    };

    // wires: 0,1,2 -> wave bits 4,2,1 | 3..8 -> lane bits 32..1 | 9,10,11 -> local 4,2,1
    #define ROT_SWEEP(base) \
        { C2 u = ld(base+0);  gate_wave<4>(s, u, t, wid, ex[0]); } \
        { C2 u = ld(base+1);  gate_wave<2>(s, u, t, wid, ex[1]); } \
        { C2 u = ld(base+2);  gate_wave<1>(s, u, t, wid, ex[0]); } \
        { C2 u = ld(base+3);  gate_lane<32>(s, u, lane); } \
        { C2 u = ld(base+4);  gate_lane<16>(s, u, lane); } \
        { C2 u = ld(base+5);  gate_lane<8>(s, u, lane); }  \
        { C2 u = ld(base+6);  gate_lane<4>(s, u, lane); }  \
        { C2 u = ld(base+7);  gate_lane<2>(s, u, lane); }  \
        { C2 u = ld(base+8);  gate_lane<1>(s, u, lane); }  \
        { C2 u = ld(base+9);  gate_local<4>(s, u); } \
        { C2 u = ld(base+10); gate_local<2>(s, u); } \
        { C2 u = ld(base+11); gate_local<1>(s, u); }

    // ================= layer 0 =================
    ROT_SWEEP(0)
    // CNOT ring r=1 (exchange buffers continue alternating: 1,0,1)
    cnot_wave_wave<4,2>(s, t, wid, ex[1]);   // (0,1)
    cnot_wave_wave<2,1>(s, t, wid, ex[0]);   // (1,2)
    cnot_wave_lane<1,32>(s, wid);            // (2,3)
    cnot_lane_lane<32,16>(s, lane);          // (3,4)
    cnot_lane_lane<16,8>(s, lane);           // (4,5)
    cnot_lane_lane<8,4>(s, lane);            // (5,6)
    cnot_lane_lane<4,2>(s, lane);            // (6,7)
    cnot_lane_lane<2,1>(s, lane);            // (7,8)
    cnot_lane_local<1,4>(s, lane);           // (8,9)
    cnot_local_local<4,2>(s);                // (9,10)
    cnot_local_local<2,1>(s);                // (10,11)
    cnot_local_wave<1,4>(s, t, ex[1]);       // (11,0)

    // ================= layer 1 ================= (buffers: 0,1,0)
    ROT_SWEEP(12)
    // CNOT ring r=2
    cnot_wave_wave<4,1>(s, t, wid, ex[1]);   // (0,2)
    cnot_wave_lane<2,32>(s, wid);            // (1,3)
    cnot_wave_lane<1,16>(s, wid);            // (2,4)
    cnot_lane_lane<32,8>(s, lane);           // (3,5)
    cnot_lane_lane<16,4>(s, lane);           // (4,6)
    cnot_lane_lane<8,2>(s, lane);            // (5,7)
    cnot_lane_lane<4,1>(s, lane);            // (6,8)
    cnot_lane_local<2,4>(s, lane);           // (7,9)
    cnot_lane_local<1,2>(s, lane);           // (8,10)
    cnot_local_local<4,1>(s);                // (9,11)
    cnot_local_wave<2,4>(s, t, ex[0]);       // (10,0)
    cnot_local_wave<1,2>(s, t, ex[1]);       // (11,1)

    #undef ROT_SWEEP

    // ---- probs -> Z expvals -> head ----
    float hwreg[NW];
    #pragma unroll
    for (int w = 0; w < NW; ++w) hwreg[w] = hw[w];
    float zhi = 0.0f;
    #pragma unroll
    for (int w = 0; w < 9; ++w)
        zhi += ((t >> (8 - w)) & 1) ? -hwreg[w] : hwreg[w];
    float acc = 0.0f;
    #pragma unroll
    for (int j = 0; j < NA; ++j) {
        float pr = s.re[j]*s.re[j] + s.im[j]*s.im[j];
        float z = zhi;
        z += (j & 4) ? -hwreg[9]  : hwreg[9];
        z += (j & 2) ? -hwreg[10] : hwreg[10];
        z += (j & 1) ? -hwreg[11] : hwreg[11];
        acc += pr * z;
    }
    #pragma unroll
    for (int off = 32; off > 0; off >>= 1) acc += __shfl_down(acc, off, 64);
    if (lane == 0) wavesum[wid] = acc;
    __syncthreads();
    if (t == 0) {
        float r = hb[0];
        #pragma unroll
        for (int wv = 0; wv < 8; ++wv) r += wavesum[wv];
        out[b] = r;
    }
}

extern "C" void kernel_launch(void* const* d_in, const int* in_sizes, int n_in,
                              void* d_out, int out_size, void* d_ws, size_t ws_size,
                              hipStream_t stream) {
    const float* x   = (const float*)d_in[0];
    const float* var = (const float*)d_in[1];
    const float* hw  = (const float*)d_in[2];
    const float* hb  = (const float*)d_in[3];
    float* out = (float*)d_out;
    qnn_kernel<<<out_size, BT, 0, stream>>>(x, var, hw, hb, out);
}

// Round 7
// 27.825 us; speedup vs baseline: 1.2570x; 1.0389x over previous
//
#include <hip/hip_runtime.h>

constexpr int NW = 12;
constexpr int BT = 512;   // 1 sample/block; state bits [wave:3][lane:6][local:3]
constexpr int NA = 8;     // amps per thread

struct C2 { float u00r,u00i,u01r,u01i,u10r,u10i,u11r,u11i; };
struct St { float re[NA]; float im[NA]; };

// DPP cross-lane: full-permutation controls, all lanes valid
template<int CTRL>
__device__ __forceinline__ float dppx(float v) {
    int r = __builtin_amdgcn_update_dpp(0, __builtin_bit_cast(int, v), CTRL, 0xF, 0xF, true);
    return __builtin_bit_cast(float, r);
}

// partner value across lane-xor M (validated in R6)
template<int M>
__device__ __forceinline__ float lxor(float v) {
    if constexpr (M == 1)      { return dppx<0xB1>(v); }            // quad_perm [1,0,3,2]
    else if constexpr (M == 2) { return dppx<0x4E>(v); }            // quad_perm [2,3,0,1]
    else if constexpr (M == 8) { return dppx<0x128>(v); }           // row_ror:8 == xor 8
    else if constexpr (M == 4) {
        int r = __builtin_amdgcn_ds_swizzle(__builtin_bit_cast(int, v), 0x101F); // xor 4
        return __builtin_bit_cast(float, r);
    } else if constexpr (M == 16) {
        int r = __builtin_amdgcn_ds_swizzle(__builtin_bit_cast(int, v), 0x401F); // xor 16
        return __builtin_bit_cast(float, r);
    } else {
        return __shfl_xor(v, 32, 64);
    }
}

// ---- Rot gate on a local bit (registers) ----
template<int LM>
__device__ __forceinline__ void gate_local(St& s, const C2& u) {
    #pragma unroll
    for (int j0 = 0; j0 < NA; ++j0) {
        if (j0 & LM) continue;
        const int j1 = j0 | LM;
        float r0=s.re[j0], m0=s.im[j0], r1=s.re[j1], m1=s.im[j1];
        s.re[j0] = u.u00r*r0 - u.u00i*m0 + u.u01r*r1 - u.u01i*m1;
        s.im[j0] = u.u00r*m0 + u.u00i*r0 + u.u01r*m1 + u.u01i*r1;
        s.re[j1] = u.u10r*r0 - u.u10i*m0 + u.u11r*r1 - u.u11i*m1;
        s.im[j1] = u.u10r*m0 + u.u10i*r0 + u.u11r*m1 + u.u11i*r1;
    }
}

// ---- Rot gate on a lane bit ----
template<int M>
__device__ __forceinline__ void gate_lane(St& s, const C2& u, int lane) {
    const bool b = (lane & M) != 0;
    const float uar = b ? u.u11r : u.u00r;
    const float uai = b ? u.u11i : u.u00i;
    const float ubr = b ? u.u10r : u.u01r;
    const float ubi = b ? u.u10i : u.u01i;
    #pragma unroll
    for (int j = 0; j < NA; ++j) {
        float pr = lxor<M>(s.re[j]);
        float pi = lxor<M>(s.im[j]);
        float r = s.re[j], m = s.im[j];
        s.re[j] = uar*r - uai*m + ubr*pr - ubi*pi;
        s.im[j] = uar*m + uai*r + ubr*pi + ubi*pr;
    }
}

// ---- transpose: swap the 3 wave bits with the 3 local bits (one barrier) ----
// store ex[j*BT+t]; load ex[wid*BT + j*64 + lane]  (involution — same code both ways)
__device__ __forceinline__ void transpose_wl(St& s, int t, int wid, int lane, float2* ex) {
    #pragma unroll
    for (int j = 0; j < NA; ++j) ex[j*BT + t] = make_float2(s.re[j], s.im[j]);
    __syncthreads();
    #pragma unroll
    for (int j = 0; j < NA; ++j) {
        float2 p = ex[wid*BT + j*64 + lane];
        s.re[j] = p.x; s.im[j] = p.y;
    }
}

// ---- CNOTs ----
template<int CM, int TM>    // ctrl local, tgt local
__device__ __forceinline__ void cnot_local_local(St& s) {
    #pragma unroll
    for (int j0 = 0; j0 < NA; ++j0) {
        if ((j0 & TM) || !(j0 & CM)) continue;
        const int j1 = j0 | TM;
        float r = s.re[j0]; s.re[j0] = s.re[j1]; s.re[j1] = r;
        float m = s.im[j0]; s.im[j0] = s.im[j1]; s.im[j1] = m;
    }
}

template<int CL, int TM>    // ctrl lane, tgt local
__device__ __forceinline__ void cnot_lane_local(St& s, int lane) {
    const bool c = (lane & CL) != 0;
    #pragma unroll
    for (int j0 = 0; j0 < NA; ++j0) {
        if (j0 & TM) continue;
        const int j1 = j0 | TM;
        float a = s.re[j0], bb = s.re[j1];
        s.re[j0] = c ? bb : a;  s.re[j1] = c ? a : bb;
        float ai = s.im[j0], bi = s.im[j1];
        s.im[j0] = c ? bi : ai; s.im[j1] = c ? ai : bi;
    }
}

template<int CM, int TL>    // ctrl local, tgt lane: shuffle only ctrl=1 slots
__device__ __forceinline__ void cnot_local_lane(St& s) {
    #pragma unroll
    for (int j = 0; j < NA; ++j) {
        if (!(j & CM)) continue;
        s.re[j] = lxor<TL>(s.re[j]);
        s.im[j] = lxor<TL>(s.im[j]);
    }
}

template<int CL, int TL>    // ctrl lane, tgt lane
__device__ __forceinline__ void cnot_lane_lane(St& s, int lane) {
    const bool c = (lane & CL) != 0;
    #pragma unroll
    for (int j = 0; j < NA; ++j) {
        float pr = lxor<TL>(s.re[j]);
        float pi = lxor<TL>(s.im[j]);
        s.re[j] = c ? pr : s.re[j];
        s.im[j] = c ? pi : s.im[j];
    }
}

template<int CW, int TL>    // ctrl wave, tgt lane (wave-uniform branch)
__device__ __forceinline__ void cnot_wave_lane(St& s, int wid) {
    if (wid & CW) {
        #pragma unroll
        for (int j = 0; j < NA; ++j) {
            s.re[j] = lxor<TL>(s.re[j]);
            s.im[j] = lxor<TL>(s.im[j]);
        }
    }
}

template<int CW, int TM>    // ctrl wave, tgt local: predicated register swap (free)
__device__ __forceinline__ void cnot_wave_local(St& s, int wid) {
    if (wid & CW) {
        #pragma unroll
        for (int j0 = 0; j0 < NA; ++j0) {
            if (j0 & TM) continue;
            const int j1 = j0 | TM;
            float r = s.re[j0]; s.re[j0] = s.re[j1]; s.re[j1] = r;
            float m = s.im[j0]; s.im[j0] = s.im[j1]; s.im[j1] = m;
        }
    }
}

template<int CL, int WM>    // ctrl lane, tgt wave: predicated LDS exchange (one barrier)
__device__ __forceinline__ void cnot_lane_wave(St& s, int t, int lane, float2* ex) {
    const bool c = (lane & CL) != 0;
    if (c) {
        #pragma unroll
        for (int j = 0; j < NA; ++j) ex[j*BT + t] = make_float2(s.re[j], s.im[j]);
    }
    __syncthreads();
    if (c) {
        const int pt = t ^ (WM << 6);
        #pragma unroll
        for (int j = 0; j < NA; ++j) {
            float2 p = ex[j*BT + pt];
            s.re[j] = p.x; s.im[j] = p.y;
        }
    }
}

template<int CM, int WM>    // ctrl local, tgt wave (one barrier)
__device__ __forceinline__ void cnot_local_wave(St& s, int t, float2* ex) {
    #pragma unroll
    for (int j = 0; j < NA; ++j) {
        if (!(j & CM)) continue;
        ex[j*BT + t] = make_float2(s.re[j], s.im[j]);
    }
    __syncthreads();
    const int pt = t ^ (WM << 6);
    #pragma unroll
    for (int j = 0; j < NA; ++j) {
        if (!(j & CM)) continue;
        float2 p = ex[j*BT + pt];
        s.re[j] = p.x; s.im[j] = p.y;
    }
}

template<int CW, int TW>    // ctrl wave, tgt wave (one barrier)
__device__ __forceinline__ void cnot_wave_wave(St& s, int t, int wid, float2* ex) {
    if (wid & CW) {
        #pragma unroll
        for (int j = 0; j < NA; ++j) ex[j*BT + t] = make_float2(s.re[j], s.im[j]);
    }
    __syncthreads();
    if (wid & CW) {
        const int pt = t ^ (TW << 6);
        #pragma unroll
        for (int j = 0; j < NA; ++j) {
            float2 p = ex[j*BT + pt];
            s.re[j] = p.x; s.im[j] = p.y;
        }
    }
}

__global__ __launch_bounds__(BT)
void qnn_kernel(const float* __restrict__ x, const float* __restrict__ var,
                const float* __restrict__ hw, const float* __restrict__ hb,
                float* __restrict__ out)
{
    // two alternating exchange buffers: 2 x 8j x 512t x float2 = 64 KiB (2 blocks/CU)
    __shared__ float2 ex[2][NA * BT];
    __shared__ float rotu[24][8];
    __shared__ float sxc[12], sxs[12];
    __shared__ float wavesum[8];

    const int t    = threadIdx.x;
    const int b    = blockIdx.x;
    const int lane = t & 63;
    const int wid  = t >> 6;

    if (t < 12) {
        float sn, cs; sincosf(0.5f * x[b*NW + t], &sn, &cs);
        sxs[t] = sn; sxc[t] = cs;
    }
    if (t < 24) {
        const float phi   = var[t*3+0];
        const float theta = var[t*3+1];
        const float omega = var[t*3+2];
        float st, ct; sincosf(0.5f*theta, &st, &ct);
        float sp, cp; sincosf(-0.5f*(phi+omega), &sp, &cp);
        float sm, cm; sincosf(-0.5f*(phi-omega), &sm, &cm);
        rotu[t][0] =  cp*ct; rotu[t][1] =  sp*ct;   // u00
        rotu[t][2] = -cm*st; rotu[t][3] =  sm*st;   // u01
        rotu[t][4] =  cm*st; rotu[t][5] =  sm*st;   // u10
        rotu[t][6] =  cp*ct; rotu[t][7] = -sp*ct;   // u11
    }
    __syncthreads();

    // product state after RY encoding (layout L0: amp = [wid|lane|j], wire w <-> bit 11-w)
    St s;
    float F = 1.0f;
    #pragma unroll
    for (int w = 0; w < 9; ++w)
        F *= ((t >> (8 - w)) & 1) ? sxs[w] : sxc[w];
    #pragma unroll
    for (int j = 0; j < NA; ++j) {
        float v = F;
        v *= (j & 4) ? sxs[9]  : sxc[9];
        v *= (j & 2) ? sxs[10] : sxc[10];
        v *= (j & 1) ? sxs[11] : sxc[11];
        s.re[j] = v; s.im[j] = 0.0f;
    }

    auto ld = [&](int g) -> C2 {
        C2 u;
        u.u00r = rotu[g][0]; u.u00i = rotu[g][1];
        u.u01r = rotu[g][2]; u.u01i = rotu[g][3];
        u.u10r = rotu[g][4]; u.u10i = rotu[g][5];
        u.u11r = rotu[g][6]; u.u11i = rotu[g][7];
        return u;
    };

    // ================= layer 0 =================
    // Rot sweep (all 12 commute): locals 9,10,11 in L0; lanes 3..8; transpose; 0,1,2 as locals (L1)
    { C2 u = ld(9);  gate_local<4>(s, u); }
    { C2 u = ld(10); gate_local<2>(s, u); }
    { C2 u = ld(11); gate_local<1>(s, u); }
    { C2 u = ld(3);  gate_lane<32>(s, u, lane); }
    { C2 u = ld(4);  gate_lane<16>(s, u, lane); }
    { C2 u = ld(5);  gate_lane<8>(s, u, lane); }
    { C2 u = ld(6);  gate_lane<4>(s, u, lane); }
    { C2 u = ld(7);  gate_lane<2>(s, u, lane); }
    { C2 u = ld(8);  gate_lane<1>(s, u, lane); }
    transpose_wl(s, t, wid, lane, ex[0]);        // -> L1: wires 0,1,2 local; 9,10,11 wave
    { C2 u = ld(0);  gate_local<4>(s, u); }
    { C2 u = ld(1);  gate_local<2>(s, u); }
    { C2 u = ld(2);  gate_local<1>(s, u); }
    // CNOT ring r=1, strict order w=0..11, in L1
    cnot_local_local<4,2>(s);                    // (0,1)
    cnot_local_local<2,1>(s);                    // (1,2)
    cnot_local_lane<1,32>(s);                    // (2,3)
    cnot_lane_lane<32,16>(s, lane);              // (3,4)
    cnot_lane_lane<16,8>(s, lane);               // (4,5)
    cnot_lane_lane<8,4>(s, lane);                // (5,6)
    cnot_lane_lane<4,2>(s, lane);                // (6,7)
    cnot_lane_lane<2,1>(s, lane);                // (7,8)
    cnot_lane_wave<1,4>(s, t, lane, ex[1]);      // (8,9)
    cnot_wave_wave<4,2>(s, t, wid, ex[0]);       // (9,10)
    cnot_wave_wave<2,1>(s, t, wid, ex[1]);       // (10,11)
    cnot_wave_local<1,4>(s, wid);                // (11,0)

    // ================= layer 1 ================= (entering in L1)
    { C2 u = ld(12); gate_local<4>(s, u); }      // wire0
    { C2 u = ld(13); gate_local<2>(s, u); }      // wire1
    { C2 u = ld(14); gate_local<1>(s, u); }      // wire2
    { C2 u = ld(15); gate_lane<32>(s, u, lane); }
    { C2 u = ld(16); gate_lane<16>(s, u, lane); }
    { C2 u = ld(17); gate_lane<8>(s, u, lane); }
    { C2 u = ld(18); gate_lane<4>(s, u, lane); }
    { C2 u = ld(19); gate_lane<2>(s, u, lane); }
    { C2 u = ld(20); gate_lane<1>(s, u, lane); }
    transpose_wl(s, t, wid, lane, ex[0]);        // -> back to L0
    { C2 u = ld(21); gate_local<4>(s, u); }      // wire9
    { C2 u = ld(22); gate_local<2>(s, u); }      // wire10
    { C2 u = ld(23); gate_local<1>(s, u); }      // wire11
    // CNOT ring r=2, strict order, in L0
    cnot_wave_wave<4,1>(s, t, wid, ex[1]);       // (0,2)
    cnot_wave_lane<2,32>(s, wid);                // (1,3)
    cnot_wave_lane<1,16>(s, wid);                // (2,4)
    cnot_lane_lane<32,8>(s, lane);               // (3,5)
    cnot_lane_lane<16,4>(s, lane);               // (4,6)
    cnot_lane_lane<8,2>(s, lane);                // (5,7)
    cnot_lane_lane<4,1>(s, lane);                // (6,8)
    cnot_lane_local<2,4>(s, lane);               // (7,9)
    cnot_lane_local<1,2>(s, lane);               // (8,10)
    cnot_local_local<4,1>(s);                    // (9,11)
    cnot_local_wave<2,4>(s, t, ex[0]);           // (10,0)
    cnot_local_wave<1,2>(s, t, ex[1]);           // (11,1)

    // ---- probs -> Z expvals -> head (L0 layout) ----
    float hwreg[NW];
    #pragma unroll
    for (int w = 0; w < NW; ++w) hwreg[w] = hw[w];
    float zhi = 0.0f;
    #pragma unroll
    for (int w = 0; w < 9; ++w)
        zhi += ((t >> (8 - w)) & 1) ? -hwreg[w] : hwreg[w];
    float acc = 0.0f;
    #pragma unroll
    for (int j = 0; j < NA; ++j) {
        float pr = s.re[j]*s.re[j] + s.im[j]*s.im[j];
        float z = zhi;
        z += (j & 4) ? -hwreg[9]  : hwreg[9];
        z += (j & 2) ? -hwreg[10] : hwreg[10];
        z += (j & 1) ? -hwreg[11] : hwreg[11];
        acc += pr * z;
    }
    #pragma unroll
    for (int off = 32; off > 0; off >>= 1) acc += __shfl_down(acc, off, 64);
    if (lane == 0) wavesum[wid] = acc;
    __syncthreads();
    if (t == 0) {
        float r = hb[0];
        #pragma unroll
        for (int wv = 0; wv < 8; ++wv) r += wavesum[wv];
        out[b] = r;
    }
}

extern "C" void kernel_launch(void* const* d_in, const int* in_sizes, int n_in,
                              void* d_out, int out_size, void* d_ws, size_t ws_size,
                              hipStream_t stream) {
    const float* x   = (const float*)d_in[0];
    const float* var = (const float*)d_in[1];
    const float* hw  = (const float*)d_in[2];
    const float* hb  = (const float*)d_in[3];
    float* out = (float*)d_out;
    qnn_kernel<<<out_size, BT, 0, stream>>>(x, var, hw, hb, out);
}

// Round 8
// 22.453 us; speedup vs baseline: 1.5578x; 1.2393x over previous
//
#include <hip/hip_runtime.h>

constexpr int NW = 12;
constexpr int BT = 512;   // 1 sample/block; state bits [wave:3][lane:6][local:3]
constexpr int NA = 8;     // amps per thread

typedef float f32x2 __attribute__((ext_vector_type(2)));

// ---- packed FP32 ops (VOP3P). Semantics guarded by runtime self-check. ----
__device__ __forceinline__ f32x2 pkmul(f32x2 a, f32x2 b) {
    f32x2 d;
    asm("v_pk_mul_f32 %0, %1, %2" : "=v"(d) : "v"(a), "v"(b));
    return d;
}
__device__ __forceinline__ f32x2 pkfma(f32x2 a, f32x2 b, f32x2 c) {
    f32x2 d;
    asm("v_pk_fma_f32 %0, %1, %2, %3" : "=v"(d) : "v"(a), "v"(b), "v"(c));
    return d;
}
// d.lo = -a.hi*b.lo + c.lo ; d.hi = a.lo*b.hi + c.hi   (complex i-part)
__device__ __forceinline__ f32x2 pkfma_swapneg(f32x2 a, f32x2 b, f32x2 c) {
    f32x2 d;
    asm("v_pk_fma_f32 %0, %1, %2, %3 op_sel:[1,0,0] op_sel_hi:[0,1,1] neg_lo:[1,0,0]"
        : "=v"(d) : "v"(a), "v"(b), "v"(c));
    return d;
}

// complex helpers, packed or scalar (splat pairs carry the value in both halves)
template<bool PK>
struct Ops {
    static __device__ __forceinline__ f32x2 cmul(f32x2 z, f32x2 ur, f32x2 ui) {
        if constexpr (PK) return pkfma_swapneg(z, ui, pkmul(z, ur));
        else {
            f32x2 r;
            r.x = ur.x * z.x - ui.x * z.y;
            r.y = ur.x * z.y + ui.x * z.x;
            return r;
        }
    }
    static __device__ __forceinline__ f32x2 cmac(f32x2 z, f32x2 ur, f32x2 ui, f32x2 acc) {
        if constexpr (PK) return pkfma_swapneg(z, ui, pkfma(z, ur, acc));
        else {
            f32x2 r;
            r.x = acc.x + ur.x * z.x - ui.x * z.y;
            r.y = acc.y + ur.x * z.y + ui.x * z.x;
            return r;
        }
    }
};

struct C2p { f32x2 r00, i00, r01, i01, r10, i10, r11, i11; };
struct St  { f32x2 z[NA]; };

// DPP cross-lane (validated R6)
template<int CTRL>
__device__ __forceinline__ float dppx(float v) {
    int r = __builtin_amdgcn_update_dpp(0, __builtin_bit_cast(int, v), CTRL, 0xF, 0xF, true);
    return __builtin_bit_cast(float, r);
}

// partner across lane-xor M. M=1,2,8: DPP. M=4,16: ds_swizzle. M=32: ds_bpermute (cached addr).
template<int M>
__device__ __forceinline__ float lxor(float v, int bp32) {
    if constexpr (M == 1)      { return dppx<0xB1>(v); }
    else if constexpr (M == 2) { return dppx<0x4E>(v); }
    else if constexpr (M == 8) { return dppx<0x128>(v); }
    else if constexpr (M == 4) {
        int r = __builtin_amdgcn_ds_swizzle(__builtin_bit_cast(int, v), 0x101F);
        return __builtin_bit_cast(float, r);
    } else if constexpr (M == 16) {
        int r = __builtin_amdgcn_ds_swizzle(__builtin_bit_cast(int, v), 0x401F);
        return __builtin_bit_cast(float, r);
    } else {
        int r = __builtin_amdgcn_ds_bpermute(bp32, __builtin_bit_cast(int, v));
        return __builtin_bit_cast(float, r);
    }
}

template<int M>
__device__ __forceinline__ f32x2 lxor2(f32x2 z, int bp32) {
    f32x2 p;
    p.x = lxor<M>(z.x, bp32);
    p.y = lxor<M>(z.y, bp32);
    return p;
}

// ---- Rot gates ----
template<bool PK, int LM>
__device__ __forceinline__ void gate_local(St& s, const C2p& u) {
    #pragma unroll
    for (int j0 = 0; j0 < NA; ++j0) {
        if (j0 & LM) continue;
        const int j1 = j0 | LM;
        f32x2 z0 = s.z[j0], z1 = s.z[j1];
        s.z[j0] = Ops<PK>::cmac(z1, u.r01, u.i01, Ops<PK>::cmul(z0, u.r00, u.i00));
        s.z[j1] = Ops<PK>::cmac(z1, u.r11, u.i11, Ops<PK>::cmul(z0, u.r10, u.i10));
    }
}

template<bool PK, int M>
__device__ __forceinline__ void gate_lane(St& s, const C2p& u, int lane, int bp32) {
    const bool b = (lane & M) != 0;
    f32x2 ar = b ? u.r11 : u.r00, ai = b ? u.i11 : u.i00;
    f32x2 br = b ? u.r10 : u.r01, bi = b ? u.i10 : u.i01;
    #pragma unroll
    for (int j = 0; j < NA; ++j) {
        f32x2 p = lxor2<M>(s.z[j], bp32);
        s.z[j] = Ops<PK>::cmac(p, br, bi, Ops<PK>::cmul(s.z[j], ar, ai));
    }
}

// ---- transpose: swap 3 wave bits with 3 local bits (one barrier; involution) ----
__device__ __forceinline__ void transpose_wl(St& s, int t, int wid, int lane, f32x2* ex) {
    #pragma unroll
    for (int j = 0; j < NA; ++j) ex[j*BT + t] = s.z[j];
    __syncthreads();
    #pragma unroll
    for (int j = 0; j < NA; ++j) s.z[j] = ex[wid*BT + j*64 + lane];
}

// ---- CNOTs (type-level only; no FLOPs to pack) ----
template<int CM, int TM>
__device__ __forceinline__ void cnot_local_local(St& s) {
    #pragma unroll
    for (int j0 = 0; j0 < NA; ++j0) {
        if ((j0 & TM) || !(j0 & CM)) continue;
        const int j1 = j0 | TM;
        f32x2 r = s.z[j0]; s.z[j0] = s.z[j1]; s.z[j1] = r;
    }
}

template<int CL, int TM>
__device__ __forceinline__ void cnot_lane_local(St& s, int lane) {
    const bool c = (lane & CL) != 0;
    #pragma unroll
    for (int j0 = 0; j0 < NA; ++j0) {
        if (j0 & TM) continue;
        const int j1 = j0 | TM;
        f32x2 a = s.z[j0], b = s.z[j1];
        s.z[j0] = c ? b : a;
        s.z[j1] = c ? a : b;
    }
}

template<int CM, int TL>
__device__ __forceinline__ void cnot_local_lane(St& s, int bp32) {
    #pragma unroll
    for (int j = 0; j < NA; ++j) {
        if (!(j & CM)) continue;
        s.z[j] = lxor2<TL>(s.z[j], bp32);
    }
}

template<int CL, int TL>
__device__ __forceinline__ void cnot_lane_lane(St& s, int lane, int bp32) {
    const bool c = (lane & CL) != 0;
    #pragma unroll
    for (int j = 0; j < NA; ++j) {
        f32x2 p = lxor2<TL>(s.z[j], bp32);
        s.z[j] = c ? p : s.z[j];
    }
}

template<int CW, int TL>
__device__ __forceinline__ void cnot_wave_lane(St& s, int wid, int bp32) {
    if (wid & CW) {
        #pragma unroll
        for (int j = 0; j < NA; ++j) s.z[j] = lxor2<TL>(s.z[j], bp32);
    }
}

template<int CW, int TM>
__device__ __forceinline__ void cnot_wave_local(St& s, int wid) {
    if (wid & CW) {
        #pragma unroll
        for (int j0 = 0; j0 < NA; ++j0) {
            if (j0 & TM) continue;
            const int j1 = j0 | TM;
            f32x2 r = s.z[j0]; s.z[j0] = s.z[j1]; s.z[j1] = r;
        }
    }
}

template<int CL, int WM>
__device__ __forceinline__ void cnot_lane_wave(St& s, int t, int lane, f32x2* ex) {
    const bool c = (lane & CL) != 0;
    if (c) {
        #pragma unroll
        for (int j = 0; j < NA; ++j) ex[j*BT + t] = s.z[j];
    }
    __syncthreads();
    if (c) {
        const int pt = t ^ (WM << 6);
        #pragma unroll
        for (int j = 0; j < NA; ++j) s.z[j] = ex[j*BT + pt];
    }
}

template<int CM, int WM>
__device__ __forceinline__ void cnot_local_wave(St& s, int t, f32x2* ex) {
    #pragma unroll
    for (int j = 0; j < NA; ++j) {
        if (!(j & CM)) continue;
        ex[j*BT + t] = s.z[j];
    }
    __syncthreads();
    const int pt = t ^ (WM << 6);
    #pragma unroll
    for (int j = 0; j < NA; ++j) {
        if (!(j & CM)) continue;
        s.z[j] = ex[j*BT + pt];
    }
}

template<int CW, int TW>
__device__ __forceinline__ void cnot_wave_wave(St& s, int t, int wid, f32x2* ex) {
    if (wid & CW) {
        #pragma unroll
        for (int j = 0; j < NA; ++j) ex[j*BT + t] = s.z[j];
    }
    __syncthreads();
    if (wid & CW) {
        const int pt = t ^ (TW << 6);
        #pragma unroll
        for (int j = 0; j < NA; ++j) s.z[j] = ex[j*BT + pt];
    }
}

// ---- full circuit (structure identical to validated R7) ----
template<bool PK>
__device__ __forceinline__ void run_all(St& s, f32x2* ex0, f32x2* ex1,
                                        const f32x2 (*rotu)[8],
                                        int t, int lane, int wid, int bp32) {
    auto ld = [&](int g) -> C2p {
        C2p u;
        u.r00 = rotu[g][0]; u.i00 = rotu[g][1];
        u.r01 = rotu[g][2]; u.i01 = rotu[g][3];
        u.r10 = rotu[g][4]; u.i10 = rotu[g][5];
        u.r11 = rotu[g][6]; u.i11 = rotu[g][7];
        return u;
    };

    // ======== layer 0: Rot sweep (L0 locals 9-11, lanes 3-8, transpose, L1 locals 0-2)
    { C2p u = ld(9);  gate_local<PK,4>(s, u); }
    { C2p u = ld(10); gate_local<PK,2>(s, u); }
    { C2p u = ld(11); gate_local<PK,1>(s, u); }
    { C2p u = ld(3);  gate_lane<PK,32>(s, u, lane, bp32); }
    { C2p u = ld(4);  gate_lane<PK,16>(s, u, lane, bp32); }
    { C2p u = ld(5);  gate_lane<PK,8>(s, u, lane, bp32); }
    { C2p u = ld(6);  gate_lane<PK,4>(s, u, lane, bp32); }
    { C2p u = ld(7);  gate_lane<PK,2>(s, u, lane, bp32); }
    { C2p u = ld(8);  gate_lane<PK,1>(s, u, lane, bp32); }
    transpose_wl(s, t, wid, lane, ex0);          // -> L1
    { C2p u = ld(0);  gate_local<PK,4>(s, u); }
    { C2p u = ld(1);  gate_local<PK,2>(s, u); }
    { C2p u = ld(2);  gate_local<PK,1>(s, u); }
    // CNOT ring r=1, strict order, in L1
    cnot_local_local<4,2>(s);                    // (0,1)
    cnot_local_local<2,1>(s);                    // (1,2)
    cnot_local_lane<1,32>(s, bp32);              // (2,3)
    cnot_lane_lane<32,16>(s, lane, bp32);        // (3,4)
    cnot_lane_lane<16,8>(s, lane, bp32);         // (4,5)
    cnot_lane_lane<8,4>(s, lane, bp32);          // (5,6)
    cnot_lane_lane<4,2>(s, lane, bp32);          // (6,7)
    cnot_lane_lane<2,1>(s, lane, bp32);          // (7,8)
    cnot_lane_wave<1,4>(s, t, lane, ex1);        // (8,9)
    cnot_wave_wave<4,2>(s, t, wid, ex0);         // (9,10)
    cnot_wave_wave<2,1>(s, t, wid, ex1);         // (10,11)
    cnot_wave_local<1,4>(s, wid);                // (11,0)

    // ======== layer 1 (entering in L1)
    { C2p u = ld(12); gate_local<PK,4>(s, u); }
    { C2p u = ld(13); gate_local<PK,2>(s, u); }
    { C2p u = ld(14); gate_local<PK,1>(s, u); }
    { C2p u = ld(15); gate_lane<PK,32>(s, u, lane, bp32); }
    { C2p u = ld(16); gate_lane<PK,16>(s, u, lane, bp32); }
    { C2p u = ld(17); gate_lane<PK,8>(s, u, lane, bp32); }
    { C2p u = ld(18); gate_lane<PK,4>(s, u, lane, bp32); }
    { C2p u = ld(19); gate_lane<PK,2>(s, u, lane, bp32); }
    { C2p u = ld(20); gate_lane<PK,1>(s, u, lane, bp32); }
    transpose_wl(s, t, wid, lane, ex0);          // -> back to L0
    { C2p u = ld(21); gate_local<PK,4>(s, u); }
    { C2p u = ld(22); gate_local<PK,2>(s, u); }
    { C2p u = ld(23); gate_local<PK,1>(s, u); }
    // CNOT ring r=2, strict order, in L0
    cnot_wave_wave<4,1>(s, t, wid, ex1);         // (0,2)
    cnot_wave_lane<2,32>(s, wid, bp32);          // (1,3)
    cnot_wave_lane<1,16>(s, wid, bp32);          // (2,4)
    cnot_lane_lane<32,8>(s, lane, bp32);         // (3,5)
    cnot_lane_lane<16,4>(s, lane, bp32);         // (4,6)
    cnot_lane_lane<8,2>(s, lane, bp32);          // (5,7)
    cnot_lane_lane<4,1>(s, lane, bp32);          // (6,8)
    cnot_lane_local<2,4>(s, lane);               // (7,9)
    cnot_lane_local<1,2>(s, lane);               // (8,10)
    cnot_local_local<4,1>(s);                    // (9,11)
    cnot_local_wave<2,4>(s, t, ex0);             // (10,0)
    cnot_local_wave<1,2>(s, t, ex1);             // (11,1)
}

__global__ __launch_bounds__(BT)
void qnn_kernel(const float* __restrict__ x, const float* __restrict__ var,
                const float* __restrict__ hw, const float* __restrict__ hb,
                float* __restrict__ out)
{
    __shared__ f32x2 ex[2][NA * BT];   // 64 KiB (2 blocks/CU)
    __shared__ f32x2 rotu[24][8];      // pre-splatted gate matrices
    __shared__ float sxc[12], sxs[12];
    __shared__ float wavesum[8];

    const int t    = threadIdx.x;
    const int b    = blockIdx.x;
    const int lane = t & 63;
    const int wid  = t >> 6;
    const int bp32 = (lane ^ 32) << 2;   // cached ds_bpermute byte address for xor-32

    // runtime self-check of packed-op semantics (exact fp32 values; asm can't fold)
    bool pk_ok;
    {
        f32x2 z = {1.0f, 2.0f}, ur2 = {3.0f, 3.0f}, ui2 = {5.0f, 5.0f}, acc = {0.25f, -0.5f};
        f32x2 r = pkfma_swapneg(z, ui2, pkfma(z, ur2, acc));
        pk_ok = (r.x == -6.75f) && (r.y == 10.5f);
    }

    if (t < 12) {
        float sn, cs; sincosf(0.5f * x[b*NW + t], &sn, &cs);
        sxs[t] = sn; sxc[t] = cs;
    }
    if (t < 24) {
        const float phi   = var[t*3+0];
        const float theta = var[t*3+1];
        const float omega = var[t*3+2];
        float st, ct; sincosf(0.5f*theta, &st, &ct);
        float sp, cp; sincosf(-0.5f*(phi+omega), &sp, &cp);
        float sm, cm; sincosf(-0.5f*(phi-omega), &sm, &cm);
        const float v0r =  cp*ct, v0i =  sp*ct;   // u00
        const float v1r = -cm*st, v1i =  sm*st;   // u01
        const float v2r =  cm*st, v2i =  sm*st;   // u10
        const float v3r =  cp*ct, v3i = -sp*ct;   // u11
        rotu[t][0] = f32x2{v0r, v0r}; rotu[t][1] = f32x2{v0i, v0i};
        rotu[t][2] = f32x2{v1r, v1r}; rotu[t][3] = f32x2{v1i, v1i};
        rotu[t][4] = f32x2{v2r, v2r}; rotu[t][5] = f32x2{v2i, v2i};
        rotu[t][6] = f32x2{v3r, v3r}; rotu[t][7] = f32x2{v3i, v3i};
    }
    __syncthreads();

    // product state after RY encoding (L0: amp = [wid|lane|j], wire w <-> bit 11-w)
    St s;
    float F = 1.0f;
    #pragma unroll
    for (int w = 0; w < 9; ++w)
        F *= ((t >> (8 - w)) & 1) ? sxs[w] : sxc[w];
    #pragma unroll
    for (int j = 0; j < NA; ++j) {
        float v = F;
        v *= (j & 4) ? sxs[9]  : sxc[9];
        v *= (j & 2) ? sxs[10] : sxc[10];
        v *= (j & 1) ? sxs[11] : sxc[11];
        s.z[j] = f32x2{v, 0.0f};
    }

    if (pk_ok) run_all<true >(s, ex[0], ex[1], rotu, t, lane, wid, bp32);
    else       run_all<false>(s, ex[0], ex[1], rotu, t, lane, wid, bp32);

    // ---- probs -> Z expvals -> head (L0 layout) ----
    float hwreg[NW];
    #pragma unroll
    for (int w = 0; w < NW; ++w) hwreg[w] = hw[w];
    float zhi = 0.0f;
    #pragma unroll
    for (int w = 0; w < 9; ++w)
        zhi += ((t >> (8 - w)) & 1) ? -hwreg[w] : hwreg[w];
    float acc = 0.0f;
    #pragma unroll
    for (int j = 0; j < NA; ++j) {
        float pr = s.z[j].x*s.z[j].x + s.z[j].y*s.z[j].y;
        float zz = zhi;
        zz += (j & 4) ? -hwreg[9]  : hwreg[9];
        zz += (j & 2) ? -hwreg[10] : hwreg[10];
        zz += (j & 1) ? -hwreg[11] : hwreg[11];
        acc += pr * zz;
    }
    #pragma unroll
    for (int off = 32; off > 0; off >>= 1) acc += __shfl_down(acc, off, 64);
    if (lane == 0) wavesum[wid] = acc;
    __syncthreads();
    if (t == 0) {
        float r = hb[0];
        #pragma unroll
        for (int wv = 0; wv < 8; ++wv) r += wavesum[wv];
        out[b] = r;
    }
}

extern "C" void kernel_launch(void* const* d_in, const int* in_sizes, int n_in,
                              void* d_out, int out_size, void* d_ws, size_t ws_size,
                              hipStream_t stream) {
    const float* x   = (const float*)d_in[0];
    const float* var = (const float*)d_in[1];
    const float* hw  = (const float*)d_in[2];
    const float* hb  = (const float*)d_in[3];
    float* out = (float*)d_out;
    qnn_kernel<<<out_size, BT, 0, stream>>>(x, var, hw, hb, out);
}